// Round 5
// baseline (108.186 us; speedup 1.0000x reference)
//
#include <hip/hip_runtime.h>
#include <math.h>

#define B_N  4
#define CIN  64
#define COUT 64
#define H_N  128
#define W_N  128

typedef _Float16 half8 __attribute__((ext_vector_type(8)));
typedef float    f32x4 __attribute__((ext_vector_type(4)));

#define KTOT   1728              // 27 groups (t*3+h) * 64 c
#define NSTEP  54                // KTOT / 32
#define WA_BYTES ((size_t)NSTEP * 4 * 64 * 8 * 2)   // 221184 B

// ---- pack weights (3,Cout,Cin,3,3) fp32 -> f16 in MFMA A-fragment order ----
// A-fragment for K-step s, m-tile mt, lane l: 8 f16 = A[m=mt*16+(l&15)][k=s*32+(l>>4)*8+j]
// k -> (t,h,c): g=k>>6, c=k&63, t=g/3, h=g%3
__global__ void wprep(const float* __restrict__ w, _Float16* __restrict__ wa) {
    int idx = blockIdx.x * 256 + threadIdx.x;        // (s, mt, lane)
    if (idx >= NSTEP * 4 * 64) return;
    int lane = idx & 63;
    int mt   = (idx >> 6) & 3;
    int s    = idx >> 8;
    int m    = mt * 16 + (lane & 15);
    int kl0  = (lane >> 4) * 8;
    _Float16 v[8];
#pragma unroll
    for (int j = 0; j < 8; ++j) {
        int k = s * 32 + kl0 + j;
        int g = k >> 6;
        int c = k & 63;
        int t = g / 3;
        int h = g % 3;
        v[j] = (_Float16)w[(((size_t)(h * COUT) + m) * CIN + c) * 9 + t];
    }
    *(int4*)&wa[(size_t)idx * 8] = *(int4*)v;
}

#define XS_STRIDE 72             // 64 c + 8 pad; lane stride 144B spreads evenly over banks
#define XS_ROW    (66 * XS_STRIDE)   // 66 x-positions (x0-1 .. x0+64)

// R5: occupancy restructure. Block = (b, y, x-half): 64 px x 64 o, 4 waves.
// Wave w: mh=w&1 (o-half), nh=w>>1 (px-half); each wave 2 m-tiles x 2 n-tiles.
// Grid 1024, LDS 28.5KB, launch_bounds(256,4) -> 4 blocks/CU = 16 waves/CU
// (R4: 512 blocks, 56KB LDS -> 2 blocks/CU = 8 waves/CU, latency-exposed:
// MfmaUtil 10%, VALUBusy 12%, Occ 19.6%). No per-tap barrier (R3: neutral).
__global__ __launch_bounds__(256, 4)
void conv_mfma(const float* __restrict__ inp, const float* __restrict__ depth,
               const _Float16* __restrict__ wa, const float* __restrict__ bias,
               const int* __restrict__ fptr, float* __restrict__ out) {
    __shared__ _Float16 Xs[3 * XS_ROW];              // 28512 B

    int bid  = blockIdx.x;
    int xh   = bid & 1;
    int y    = (bid >> 1) & (H_N - 1);
    int b    = bid >> 8;
    int x0   = xh * 64;
    int tid  = threadIdx.x;
    int lane = tid & 63;
    int wid  = tid >> 6;
    int mh   = wid & 1;          // o-half
    int nh   = wid >> 1;         // px-half within the 64-px tile
    int ln15 = lane & 15;
    int quad = lane >> 4;

    // ---- stage 3 input rows (dy=-1,0,1), x0-1..x0+64, transposed [x][c] f16 ----
    {
        int xl0 = tid & 63;
        int cq  = tid >> 6;                          // c base = cq*16
#pragma unroll
        for (int e = 0; e < 2; ++e) {
            int xl = (e == 0) ? xl0 : 64 + xl0;      // e==1 covers xl 64,65
            if (e == 1 && xl0 >= 2) break;
            int gx = x0 - 1 + xl;
            for (int dyi = 0; dyi < 3; ++dyi) {
                int yy = y + dyi - 1;
                _Float16 buf[16];
                if (yy >= 0 && yy < H_N && gx >= 0 && gx < W_N) {
                    const float* src = inp + (((size_t)b * CIN + cq * 16) * H_N + yy) * W_N + gx;
#pragma unroll
                    for (int cc = 0; cc < 16; ++cc)
                        buf[cc] = (_Float16)src[(size_t)cc * H_N * W_N];
                } else {
#pragma unroll
                    for (int cc = 0; cc < 16; ++cc) buf[cc] = (_Float16)0.f;
                }
                _Float16* dst = &Xs[dyi * XS_ROW + xl * XS_STRIDE + cq * 16];
                *(int4*)&dst[0] = *(int4*)&buf[0];
                *(int4*)&dst[8] = *(int4*)&buf[8];
            }
        }
    }

    // ---- per-lane h-selection packs (exact fp64, identical to R1..R4) ----
    double fd = (double)(*fptr);
    unsigned hpk[2];
#pragma unroll
    for (int nt = 0; nt < 2; ++nt) {
        int x = x0 + nh * 32 + nt * 16 + ln15;
        float d0f = depth[((size_t)b * H_N + y) * W_N + x];
        double dd = (double)d0f;
        double s0 = dd / fd;
        unsigned pk = 0;
        for (int t = 0; t < 9; ++t) {
            int dy = t / 3 - 1, dx = t % 3 - 1;
            int yy = y + dy, xx = x + dx;
            float dwf = (yy >= 0 && yy < H_N && xx >= 0 && xx < W_N)
                        ? depth[((size_t)b * H_N + yy) * W_N + xx] : 0.f;
            int h = -1;
            if (s0 > 0.0) {
                double u  = ((double)dwf - dd) / s0 + 1.5;
                double uf = floor(u);
                if (uf >= 0.0 && uf <= 2.0) h = (int)uf;
            }
            pk |= (unsigned)(h + 1) << (2 * t);
        }
        hpk[nt] = pk;
    }

    __syncthreads();

    // ---- MFMA main loop: 9 taps x (3 h x 2 kk), 2 m-tiles x 2 n-tiles ----
    f32x4 acc[2][2];
#pragma unroll
    for (int mt = 0; mt < 2; ++mt)
#pragma unroll
        for (int nt = 0; nt < 2; ++nt) acc[mt][nt] = (f32x4){0.f, 0.f, 0.f, 0.f};

    const half8* wa8 = (const half8*)wa;   // frag index: (s*4 + mt4)*64 + lane

    for (int t = 0; t < 9; ++t) {
        int dyi = t / 3;
        int dx  = t % 3 - 1;
        int boff0 = dyi * XS_ROW + (nh * 32 + 0  + ln15 + dx + 1) * XS_STRIDE + quad * 8;
        int boff1 = dyi * XS_ROW + (nh * 32 + 16 + ln15 + dx + 1) * XS_STRIDE + quad * 8;
        int hb0 = (hpk[0] >> (2 * t)) & 3;
        int hb1 = (hpk[1] >> (2 * t)) & 3;

        // batch-load this tap's A-fragments: 6 K-steps x 2 m-tiles (this o-half)
        half8 A[6][2];
        {
            const half8* base = wa8 + ((size_t)t * 6 * 4 + mh * 2) * 64 + lane;
#pragma unroll
            for (int j = 0; j < 6; ++j)
#pragma unroll
                for (int mt = 0; mt < 2; ++mt)
                    A[j][mt] = base[(j * 4 + mt) * 64];
        }

#pragma unroll
        for (int h = 0; h < 3; ++h) {
            bool m0 = (hb0 == h + 1);
            bool m1 = (hb1 == h + 1);
#pragma unroll
            for (int kk = 0; kk < 2; ++kk) {
                int j = h * 2 + kk;
                half8 b0 = *(const half8*)&Xs[boff0 + kk * 32];
                half8 b1 = *(const half8*)&Xs[boff1 + kk * 32];
                half8 z  = {(_Float16)0.f, (_Float16)0.f, (_Float16)0.f, (_Float16)0.f,
                            (_Float16)0.f, (_Float16)0.f, (_Float16)0.f, (_Float16)0.f};
                b0 = m0 ? b0 : z;
                b1 = m1 ? b1 : z;
#pragma unroll
                for (int mt = 0; mt < 2; ++mt) {
                    acc[mt][0] = __builtin_amdgcn_mfma_f32_16x16x32_f16(A[j][mt], b0, acc[mt][0], 0, 0, 0);
                    acc[mt][1] = __builtin_amdgcn_mfma_f32_16x16x32_f16(A[j][mt], b1, acc[mt][1], 0, 0, 0);
                }
            }
        }
    }

    // ---- epilogue: D[m=o: quad*4+r][n=pixel: lane&15] + bias ----
#pragma unroll
    for (int mt = 0; mt < 2; ++mt) {
#pragma unroll
        for (int nt = 0; nt < 2; ++nt) {
            int x = x0 + nh * 32 + nt * 16 + ln15;
#pragma unroll
            for (int r = 0; r < 4; ++r) {
                int o = mh * 32 + mt * 16 + quad * 4 + r;
                out[(((size_t)b * COUT + o) * H_N + y) * W_N + x] = acc[mt][nt][r] + bias[o];
            }
        }
    }
}

// ---- fallback scalar kernel (used only if ws too small) ----
__global__ __launch_bounds__(256)
void conv25d(const float* __restrict__ inp, const float* __restrict__ depth,
             const float* __restrict__ wsrc, const float* __restrict__ bias,
             const int* __restrict__ fptr, float* __restrict__ out) {
    int bid = blockIdx.x;
    int xt  = bid & 3;
    int y   = (bid >> 2) & (H_N - 1);
    int b   = bid >> 9;
    int o   = threadIdx.x & 63;
    int q   = threadIdx.x >> 6;
    int x0  = xt * 32 + q * 8;
    double fd = (double)(*fptr);
    float acc[8];
    float bv = bias[o];
#pragma unroll
    for (int i = 0; i < 8; ++i) acc[i] = bv;
    const float* dcen = depth + ((size_t)b * H_N + y) * W_N;
    float d0[8];
#pragma unroll
    for (int i = 0; i < 8; ++i) d0[i] = dcen[x0 + i];
    for (int t = 0; t < 9; ++t) {
        int dy = t / 3 - 1, dx = t % 3 - 1;
        int yy = y + dy;
        if (yy < 0 || yy >= H_N) continue;
        const float* drow = depth + ((size_t)b * H_N + yy) * W_N;
        int hsel[8];
#pragma unroll
        for (int i = 0; i < 8; ++i) {
            int xx = x0 + i + dx;
            int h = -1;
            if (xx >= 0 && xx < W_N) {
                double dd = (double)d0[i];
                double s0 = dd / fd;
                if (s0 > 0.0) {
                    double u = ((double)drow[xx] - dd) / s0 + 1.5;
                    double uf = floor(u);
                    if (uf >= 0.0 && uf <= 2.0) h = (int)uf;
                }
            }
            hsel[i] = h;
        }
        const float* irow = inp + ((size_t)b * CIN * H_N + yy) * W_N;
        for (int c = 0; c < CIN; ++c) {
            const float* wb = wsrc + ((size_t)o * CIN + c) * 9 + t;
            float w0 = wb[0], w1 = wb[(size_t)COUT * CIN * 9], w2 = wb[2 * (size_t)COUT * CIN * 9];
            const float* ir = irow + (size_t)c * H_N * W_N;
#pragma unroll
            for (int i = 0; i < 8; ++i) {
                int h = hsel[i];
                if (h >= 0) {
                    float wv = (h == 0) ? w0 : ((h == 1) ? w1 : w2);
                    acc[i] = fmaf(ir[x0 + i + dx], wv, acc[i]);
                }
            }
        }
    }
    float* orow = out + (((size_t)b * COUT + o) * H_N + y) * W_N;
#pragma unroll
    for (int i = 0; i < 8; ++i) orow[x0 + i] = acc[i];
}

extern "C" void kernel_launch(void* const* d_in, const int* in_sizes, int n_in,
                              void* d_out, int out_size, void* d_ws, size_t ws_size,
                              hipStream_t stream) {
    const float* inp   = (const float*)d_in[0];
    const float* depth = (const float*)d_in[1];
    const float* w     = (const float*)d_in[2];
    const float* bias  = (const float*)d_in[3];
    const int*   f     = (const int*)d_in[4];
    float* out = (float*)d_out;

    if (ws_size >= WA_BYTES) {
        _Float16* wa = (_Float16*)d_ws;
        wprep<<<NSTEP, 256, 0, stream>>>(w, wa);
        conv_mfma<<<B_N * H_N * 2, 256, 0, stream>>>(inp, depth, wa, bias, f, out);
    } else {
        conv25d<<<B_N * H_N * (W_N / 32), 256, 0, stream>>>(inp, depth, w, bias, f, out);
    }
}